// Round 4
// baseline (265.175 us; speedup 1.0000x reference)
//
#include <hip/hip_runtime.h>
#include <math.h>

#define B   32
#define N   512
#define M   512
#define DIM 64

#define INF __builtin_huge_valf()
#define LOG2E 1.44269504088896340736f
#define LN2   0.69314718055994530942f

#define NDIAG_ELEMS (N * M)         /* packed diag layout size per batch */

#if __has_builtin(__builtin_amdgcn_exp2f)
#define fast_exp2 __builtin_amdgcn_exp2f
#else
#define fast_exp2 exp2f
#endif
#if __has_builtin(__builtin_amdgcn_logf)
#define fast_log2 __builtin_amdgcn_logf   /* v_log_f32 computes log2 */
#else
#define fast_log2 log2f
#endif

__device__ __forceinline__ float readlane_f(float v, int srcLane) {
    return __uint_as_float(__builtin_amdgcn_readlane(__float_as_uint(v), srcLane));
}

// Packed anti-diagonal layout. Diag t = i + j (i,j 1-based), t in [2, 1024].
// off(t) closed form; entry for row i at off(t) + (i-1) - max(0, t-513).
__device__ __forceinline__ int diag_off(int t) {
    return (t <= 513) ? (((t - 2) * (t - 1)) >> 1)
                      : (NDIAG_ELEMS - (((1025 - t) * (1026 - t)) >> 1));
}

// ---------------------------------------------------------------------------
// Kernel 1: D'[t-diag packed] = (||x_i||^2 + ||y_j||^2 - 2<x_i,y_j>) * log2(e)
// (unchanged from round 3 — correct & adequate)
// ---------------------------------------------------------------------------
__global__ __launch_bounds__(256) void pairdist_kernel(const float* __restrict__ X,
                                                       const float* __restrict__ Y,
                                                       float* __restrict__ Dout) {
    const int b  = blockIdx.z;
    const int r0 = blockIdx.y * 64;
    const int c0 = blockIdx.x * 64;

    __shared__ float Xt[DIM][68];
    __shared__ float Yt[DIM][68];
    __shared__ float Ct[64][66];

    const int tid = threadIdx.x;
    {
        const int lr = tid >> 4;
        const int lc = (tid & 15) << 2;
        const float* xp = X + ((size_t)b * N + r0) * DIM;
        const float* yp = Y + ((size_t)b * M + c0) * DIM;
        #pragma unroll
        for (int rr = 0; rr < 64; rr += 16) {
            const int r = lr + rr;
            float4 xv = *(const float4*)(xp + (size_t)r * DIM + lc);
            Xt[lc + 0][r] = xv.x;
            Xt[lc + 1][r] = xv.y;
            Xt[lc + 2][r] = xv.z;
            Xt[lc + 3][r] = xv.w;
            float4 yv = *(const float4*)(yp + (size_t)r * DIM + lc);
            Yt[lc + 0][r] = yv.x;
            Yt[lc + 1][r] = yv.y;
            Yt[lc + 2][r] = yv.z;
            Yt[lc + 3][r] = yv.w;
        }
    }
    __syncthreads();

    const int tx = (tid & 15) << 2;
    const int ty = (tid >> 4) << 2;

    float acc[4][4] = {};
    float xs2[4] = {};
    float ys2[4] = {};

    #pragma unroll 4
    for (int d = 0; d < DIM; ++d) {
        float4 xv = *(const float4*)&Xt[d][ty];
        float4 yv = *(const float4*)&Yt[d][tx];
        float xa[4] = {xv.x, xv.y, xv.z, xv.w};
        float ya[4] = {yv.x, yv.y, yv.z, yv.w};
        #pragma unroll
        for (int a = 0; a < 4; ++a) {
            xs2[a] = fmaf(xa[a], xa[a], xs2[a]);
            ys2[a] = fmaf(ya[a], ya[a], ys2[a]);
            #pragma unroll
            for (int c = 0; c < 4; ++c)
                acc[a][c] = fmaf(xa[a], ya[c], acc[a][c]);
        }
    }

    #pragma unroll
    for (int a = 0; a < 4; ++a)
        #pragma unroll
        for (int c = 0; c < 4; ++c)
            Ct[ty + a][tx + c] = (xs2[a] + ys2[c] - 2.0f * acc[a][c]) * LOG2E;

    __syncthreads();

    const int aa   = tid & 63;
    const int dgrp = tid >> 6;
    float* __restrict__ Dp = Dout + (size_t)b * NDIAG_ELEMS;
    #pragma unroll
    for (int g = 0; g < 32; ++g) {
        const int td = g * 4 + dgrp;
        const int bb = td - aa;
        if (td < 127 && bb >= 0 && bb < 64) {
            const int t   = r0 + c0 + td + 2;
            const int sub = (t > 513) ? (t - 513) : 0;
            Dp[diag_off(t) + (r0 + aa) - sub] = Ct[aa][bb];
        }
    }
}

// ---------------------------------------------------------------------------
// Kernel 2: soft-DTW DP. 1 block/batch, 8 waves x 64 lanes, ONE row per lane
// (wave w owns rows 64w+1..64w+64). Chunks of 32 diagonals, wave w runs
// chunk c at superstep c+w (39 supersteps). 2 waves/SIMD -> TLP hides
// shfl/load latency. Per step: 1 shfl (u2(t)=u1(t-1) identity), 1 coalesced
// dword load (packed-diag layout, depth-8 register queue, scalar-clamped
// address), softmin = 9 VALU + 3 trans. Fully-invalid chunks skipped
// (valid band = 576 diagonals -> 18 active chunks/wave). Validity masking
// only in the 4 edge chunks (fast path for 14 interior chunks).
// ---------------------------------------------------------------------------

// uniform packed index base for diag t (includes -sub), clamped so that
// base + row0 (row0 in [0,511]) always stays inside the 32 MB buffer.
#define DIAG_BASE(pt)                                                         \
    (((pt) <= 513) ? ((((pt) - 2) * ((pt) - 1)) >> 1)                         \
                   : (NDIAG_ELEMS - (((1025 - (pt)) * (1026 - (pt))) >> 1)    \
                      - ((pt) - 513)))

#define DTW_STEP(kk, MASKED) do {                                             \
    const int t = t0 + (kk);                                                  \
    const float u1 = (lane == 0) ? readlane_f(vchunk, (kk) + 1) : sh;         \
    const float av = u1c, bv = u1, cv = p1;                                   \
    const float lo  = fminf(fminf(av, bv), cv);                               \
    const float hi  = fmaxf(fmaxf(av, bv), cv);                               \
    const float mid = __builtin_amdgcn_fmed3f(av, bv, cv);                    \
    float r = q[(kk) & 7] + lo -                                              \
              fast_log2(1.0f + fast_exp2(lo - mid) + fast_exp2(lo - hi));     \
    if (MASKED) {                                                             \
        const bool valid = (t > i) && (t <= i + M);                           \
        r = valid ? r : INF;                                                  \
        if (t == N + M) res = r;                                              \
    }                                                                         \
    sh = __shfl_up(r, 1);                                                     \
    if (lane == 63) ringw[t & 127] = r;                                       \
    u1c = u1;                                                                 \
    p1  = r;                                                                  \
    {   /* prefetch D for step t+8 into the slot just freed */                \
        const int pt = t + 8;                                                 \
        int U = DIAG_BASE(pt);                                                \
        U = max(0, min(U, NDIAG_ELEMS - 512));                                \
        q[(kk) & 7] = Dp[U + row0];                                           \
    }                                                                         \
} while (0)

__global__ __launch_bounds__(512) void dtw_kernel(const float* __restrict__ Dmat,
                                                  float* __restrict__ out) {
    const int b = blockIdx.x;
    const float* __restrict__ Dp = Dmat + (size_t)b * NDIAG_ELEMS;

    __shared__ float ring[8][128];

    const int tid  = threadIdx.x;
    const int w    = tid >> 6;
    const int lane = tid & 63;
    const int row0 = 64 * w + lane;   // 0-based row index
    const int i    = row0 + 1;        // 1-based row

    for (int k = tid; k < 8 * 128; k += 512) (&ring[0][0])[k] = INF;
    __syncthreads();

    float* __restrict__ ringw = ring[w];
    const float* __restrict__ ringr = ring[(w + 7) & 7];

    const int cfirst = 2 * w;                 // first chunk with any valid cell
    const int clast  = min(31, 2 * w + 17);   // last chunk with any valid cell

    // D prefetch queue, depth 8, starting at the wave's first active diagonal
    float q[8];
    {
        int pt = 32 * cfirst + 2;
        #pragma unroll
        for (int p = 0; p < 8; ++p, ++pt) {
            int U = DIAG_BASE(pt);
            U = max(0, min(U, NDIAG_ELEMS - 512));
            q[p] = Dp[U + row0];
        }
    }

    float p1 = INF;    // own R[i, j-1]
    float u1c = INF;   // lane-1's c(t-2)  (previous step's u1)
    float sh  = INF;   // pending shfl result = lane-1's c(t-1)
    float res = 0.0f;

    for (int s = 0; s < 39; ++s) {
        const int c = s - w;
        if (c >= cfirst && c <= clast) {
            const int t0 = 32 * c + 2;
            // boundary-row values (producer wave w-1) for steps t0-2 .. t0+61
            float vchunk;
            if (w == 0) {
                vchunk = (c == 0 && lane == 0) ? 0.0f : INF;  // R[0,j]: 0 at j=0
            } else {
                vchunk = ringr[(t0 - 2 + lane) & 127];
                // entries past producer's valid band (j' > 512) may be stale
                if (t0 - 2 + lane > 64 * w + 512) vchunk = INF;
            }
            if (c == cfirst) {
                // seed the u2-chain: lane0's u2(t0) = producer c(t0-2)
                const float v0 = readlane_f(vchunk, 0);
                u1c = (lane == 0) ? v0 : INF;
                sh  = INF;
                p1  = INF;
            }
            if (c >= 2 * w + 2 && c <= 2 * w + 15) {
                #pragma unroll
                for (int kk = 0; kk < 32; ++kk) DTW_STEP(kk, false);
            } else {
                #pragma unroll
                for (int kk = 0; kk < 32; ++kk) DTW_STEP(kk, true);
            }
        }
        __syncthreads();
    }

    if (w == 7 && lane == 63) out[b] = res * LN2;
}

extern "C" void kernel_launch(void* const* d_in, const int* in_sizes, int n_in,
                              void* d_out, int out_size, void* d_ws, size_t ws_size,
                              hipStream_t stream) {
    const float* X = (const float*)d_in[0];
    const float* Y = (const float*)d_in[1];
    float* outp = (float*)d_out;
    float* Dmat = (float*)d_ws;   // B*N*M*4 = 32 MB, packed-diagonal layout

    dim3 g1(M / 64, N / 64, B);
    pairdist_kernel<<<g1, dim3(256), 0, stream>>>(X, Y, Dmat);
    dtw_kernel<<<dim3(B), dim3(512), 0, stream>>>(Dmat, outp);
}